// Round 10
// baseline (97.216 us; speedup 1.0000x reference)
//
#include <hip/hip_runtime.h>
#include <hip/hip_bf16.h>
#include <math.h>

// Problem constants
#define B_     2
#define CIN    32
#define HH     512
#define WW     512
#define HID    768
#define SZ     16
#define NPATCH 1024      // 32x32 patch grid
#define KDIM   8192      // CIN*SZ*SZ
#define NCLS   21
#define LAT    128
#define LC     2688      // LAT*NCLS
#define NP     (B_ * NPATCH)   // 2048 patch rows

// prep-kernel block ranges (classlat FIRST: longest serial chain)
#define NB_CL  63        // NCLS*3 : classlat (cls, 256-wide d-segment), norms inline
#define NB_W4  1536      // HID*KDIM/16/256  (4 float4 per thread)

typedef __attribute__((ext_vector_type(8))) short short8;   // 8 bf16 (4 VGPR)
typedef __attribute__((ext_vector_type(4))) float f32x4;

// RNE float->bf16
__device__ __forceinline__ ushort f2bf(float f) {
    union { float f; unsigned u; } v; v.f = f;
    unsigned r = (v.u + 0x7fff + ((v.u >> 16) & 1)) >> 16;
    return (ushort)r;
}
__device__ __forceinline__ float bf2f(ushort u) {
    union { unsigned u; float f; } v; v.u = (unsigned)u << 16;
    return v.f;
}

__device__ __forceinline__ void gload16(const void* g, void* l) {
    __builtin_amdgcn_global_load_lds(
        (const __attribute__((address_space(1))) unsigned int*)g,
        (__attribute__((address_space(3))) unsigned int*)l, 16, 0, 0);
}

// pack 2 f32 -> 1 u32 of 2 bf16 (RNE); compiler emits v_cvt_pk (m240)
__device__ __forceinline__ unsigned pk2bf(float a, float b) {
    union { __hip_bfloat162 h; unsigned u; } cv;
    cv.h = __float22bfloat162_rn(make_float2(a, b));
    return cv.u;
}

// ---------------------------------------------------------------------------
// Prep kernel (round-9 version, x untouched): conv_w + classlat only, ~80MB.
// ---------------------------------------------------------------------------
__global__ __launch_bounds__(256) void k_prep(const float* __restrict__ w,
                                              const float* __restrict__ lat,
                                              ushort* __restrict__ wb,
                                              float* __restrict__ classlat) {
    const int bid = blockIdx.x;
    const int t   = threadIdx.x;

    if (bid < NB_CL) {
        // ---- classlat with inline row norms ----
        const int cls  = bid / 3;
        const int dseg = bid % 3;
        const int lane = t & 63, wvv = t >> 6;
        __shared__ float sc_sh[LAT];

        for (int q = 0; q < 32; q += 2) {
            int u0 = wvv * 32 + q;
            const float* r0 = lat + (size_t)(u0 * NCLS + cls) * HID;
            const float* r1 = lat + (size_t)((u0 + 1) * NCLS + cls) * HID;
            float s0 = 0.f, s1 = 0.f;
#pragma unroll
            for (int e = 0; e < HID / 64; ++e) {
                float a = r0[lane + e * 64]; s0 += a * a;
                float b2 = r1[lane + e * 64]; s1 += b2 * b2;
            }
#pragma unroll
            for (int off = 32; off >= 1; off >>= 1) {
                s0 += __shfl_xor(s0, off, 64);
                s1 += __shfl_xor(s1, off, 64);
            }
            if (lane == 0) {
                sc_sh[u0]     = 1.0f / (128.0f * sqrtf(s0));
                sc_sh[u0 + 1] = 1.0f / (128.0f * sqrtf(s1));
            }
        }
        __syncthreads();

        const float* src = lat + (size_t)cls * HID + dseg * 256 + t;
        float a = 0.f;
        for (int u0 = 0; u0 < LAT; u0 += 8) {
            float v[8];
#pragma unroll
            for (int q = 0; q < 8; ++q)
                v[q] = src[(size_t)(u0 + q) * (NCLS * HID)];
#pragma unroll
            for (int q = 0; q < 8; ++q) a += v[q] * sc_sh[u0 + q];
        }
        classlat[cls * HID + dseg * 256 + t] = a;
    } else {
        // ---- conv_w convert (coalesced both sides, 4 loads in flight) ----
        const int cb = bid - NB_CL;
        float4 vv[4];
#pragma unroll
        for (int k = 0; k < 4; ++k)
            vv[k] = *(const float4*)(w + ((size_t)cb * 1024 + k * 256 + t) * 4);
#pragma unroll
        for (int k = 0; k < 4; ++k) {
            ushort4 o;
            o.x = f2bf(vv[k].x); o.y = f2bf(vv[k].y);
            o.z = f2bf(vv[k].z); o.w = f2bf(vv[k].w);
            *(ushort4*)(wb + ((size_t)cb * 1024 + k * 256 + t) * 4) = o;
        }
    }
}

// ---------------------------------------------------------------------------
// MFMA GEMM, ROUND-10: f32 x read DIRECTLY, inside the round-4 PROVEN loop.
// patch[p][d] = sum_k x-as-A[p][k] * wb[d][k],  k = c*256 + i*16 + j.
// 128x128 tile, BK=64, 4 waves (2x2), wave 64x64 via 4x4 mfma 16x16x32 bf16.
// Single-buffered, 2 barriers/K-step, grid (16,6,8)=768 = 3 blk/CU BALANCED
// (round-9's 384-block grid was 1.5/CU: +33% makespan — one of 3 regressions).
// A: f32 LDS [128][64] (32KB), filled by gload16 with per-lane SOURCE gather
//    (round-8 mechanism).  32B-granule XOR: stored 16B-chunk e of row r holds
//    logical chunk e ^ (2*(r&7)).  Read: logical f32 k s*32+fq*8..+7 lives at
//    col 8*((s*4+fq)^(fr&7)) .. +7 — contiguous 8 f32 (2x b128), slot
//    structure identical to the round-6 uniform pattern (worst 2-way lo/hi).
//    Fragment build: 2x ds_read_b128 + 4 cvt_pk per af.
//    Wave staging issue = 4 x 256B contiguous segments (coalesced).
// B: byte-identical to round 4 — bf16 wb, gload16 + XOR swizzle, [128][64].
//    (round-9's unswizzled BK=32 B was an 8-way conflict — regression #2;
//    BK=32 also halved MFMA/barrier — regression #3.)
// LDS total 48KB -> 3 blk/CU.  T1 remap: each XCD owns one split-K slice
// (c in [bz*4,bz*4+4)) so x is HBM-read once; A panel/bx = 1MB f32 L2-resident.
// Output layout: pbuf[p][z][d] (unchanged).
// ---------------------------------------------------------------------------
template <int SPLITK>
__global__ __launch_bounds__(256) void k_gemm(const float* __restrict__ x,
                                              const ushort* __restrict__ wb,
                                              ushort* __restrict__ pbuf) {
    constexpr int KS = KDIM / SPLITK;
    __shared__ float  Af[128 * 64];    // 32 KB
    __shared__ ushort Bls[128 * 64];   // 16 KB

    // ---- T1 remap: grid (16, 6, SPLITK), nwg = 96*SPLITK (always %8==0) ----
    const int flat = blockIdx.x + 16 * (blockIdx.y + 6 * blockIdx.z);
    constexpr int nwg = 96 * SPLITK;
    const int wg = (flat & 7) * (nwg >> 3) + (flat >> 3);
    const int bz = wg / 96;
    const int rr = wg - bz * 96;
    const int by = rr % 6;       // by-fastest: consecutive blocks share the A panel
    const int bx = rr / 6;       // 0..15

    const int tid  = threadIdx.x;
    const int wv   = tid >> 6;         // 0..3
    const int lane = tid & 63;
    const int wm   = (wv >> 1) * 64;
    const int wn   = (wv & 1) * 64;

    const int bxb = bx >> 3;           // batch index
    const int ph0 = (bx & 7) * 4;      // first ph of this tile (4 ph rows)

    const size_t bbase = ((size_t)by * 128) * KDIM + (size_t)bz * KS;

    // ---- B staging lanes (round-4 verbatim) ----
    const int srow  = wv * 8 + (lane >> 3);                    // + q*32
    const int skoff = (((lane & 7) ^ (lane >> 3)) * 8);        // swizzled src elem

    // ---- A gather: per-lane invariant source offset (f32 elems) ----
    // chunk n = q*256+tid: r = n>>4 = q*16+(tid>>4), e = n&15 = tid&15
    // e_src = e ^ (2*(r&7));  r&7 = (tid>>4)&7  (q*16 == 0 mod 8)
    const int esrc = (tid & 15) ^ (2 * ((tid >> 4) & 7));
    const size_t alane = (size_t)(tid >> 4) * 16        // pw*16 (lane part)
                       + (size_t)(esrc >> 2) * 512      // i_rel rows
                       + (size_t)(esrc & 3) * 4;        // j quad
    const float* xA0 = x + (size_t)bxb * 8388608 + (size_t)ph0 * 8192 + alane;

    f32x4 acc[4][4];
#pragma unroll
    for (int m = 0; m < 4; ++m)
#pragma unroll
        for (int n = 0; n < 4; ++n) acc[m][n] = (f32x4)(0.f);

    const int fr = lane & 15, fq = lane >> 4;
    const int frk = fr & 7;
    const int frx = frk * 8;        // B read-side XOR (ushort elems)

    for (int kk = 0; kk < KS; kk += 64) {
        const int gk = bz * KS + kk;            // global k, multiple of 64
        const int c  = gk >> 8;                 // input channel
        const int i0 = (gk >> 4) & 15;          // 0,4,8,12
        const float* xs = xA0 + (size_t)c * 262144 + (size_t)i0 * 512;

        // ---- A staging: 2048 chunks, 8/thread; wave = 4 x 256B segments ----
#pragma unroll
        for (int q = 0; q < 8; ++q)
            gload16(xs + (size_t)(q >> 1) * 8192 + (size_t)(q & 1) * 256,
                    &Af[q * 1024 + wv * 256]);
        // ---- B staging (round-4 verbatim) ----
#pragma unroll
        for (int q = 0; q < 4; ++q) {
            const int row = q * 32 + srow;
            gload16(&wb[bbase + (size_t)row * KDIM + kk + skoff],
                    &Bls[q * 2048 + wv * 512]);
        }
        __syncthreads();   // drains vmcnt: tiles ready

#pragma unroll
        for (int s = 0; s < 2; ++s) {
            short8 af[4], bf[4];
#pragma unroll
            for (int m = 0; m < 4; ++m) {
                const float* ap = &Af[(wm + m * 16 + fr) * 64
                                      + 8 * ((s * 4 + fq) ^ frk)];
                f32x4 lo = *(const f32x4*)ap;         // logical k s*32+fq*8..+3
                f32x4 hi = *(const f32x4*)(ap + 4);   // +4..+7
                union { unsigned u[4]; short8 s8; } cv;
                cv.u[0] = pk2bf(lo[0], lo[1]);
                cv.u[1] = pk2bf(lo[2], lo[3]);
                cv.u[2] = pk2bf(hi[0], hi[1]);
                cv.u[3] = pk2bf(hi[2], hi[3]);
                af[m] = cv.s8;
            }
#pragma unroll
            for (int n = 0; n < 4; ++n)
                bf[n] = *(const short8*)&Bls[(wn + n * 16 + fr) * 64
                                             + ((s * 32 + fq * 8) ^ frx)];
#pragma unroll
            for (int m = 0; m < 4; ++m)
#pragma unroll
                for (int n = 0; n < 4; ++n)
                    acc[m][n] = __builtin_amdgcn_mfma_f32_16x16x32_bf16(af[m], bf[n], acc[m][n], 0, 0, 0);
        }
        __syncthreads();
    }

#pragma unroll
    for (int m = 0; m < 4; ++m) {
#pragma unroll
        for (int n = 0; n < 4; ++n) {
            int col = by * 128 + wn + n * 16 + fr;
#pragma unroll
            for (int j = 0; j < 4; ++j) {
                int row = bx * 128 + wm + m * 16 + fq * 4 + j;
                pbuf[((size_t)row * SPLITK + bz) * HID + col] = f2bf(acc[m][n][j]);
            }
        }
    }
}

// ---------------------------------------------------------------------------
// Per-patch epilogue: stage the patch's contiguous [SPLITK][HID] bf16 partials
// into LDS (coalesced 16B loads), sum + bias -> norm -> 21 dots ->
// masked exp(2*sim) -> partial[p].
// ---------------------------------------------------------------------------
template <int SPLITK>
__global__ __launch_bounds__(256) void k_final(const ushort* __restrict__ pbuf,
                                               const float* __restrict__ conv_b,
                                               const float* __restrict__ classlat,
                                               const int* __restrict__ mask,
                                               float* __restrict__ partial) {
    const int p = blockIdx.x;        // 0..2047
    const int b = p >> 10, n = p & 1023;
    const int t = threadIdx.x;
    const int lane = t & 63, wv = t >> 6;

    __shared__ ushort sh[SPLITK * HID];
    const ushort* pb = pbuf + (size_t)p * (SPLITK * HID);
    for (int i = t; i < SPLITK * HID / 8; i += 256)
        *(short8*)&sh[i * 8] = *(const short8*)&pb[(size_t)i * 8];
    __syncthreads();

    float f0 = conv_b[t], f1 = conv_b[t + 256], f2 = conv_b[t + 512];
#pragma unroll
    for (int z = 0; z < SPLITK; ++z) {
        f0 += bf2f(sh[z * HID + t]);
        f1 += bf2f(sh[z * HID + t + 256]);
        f2 += bf2f(sh[z * HID + t + 512]);
    }

    __shared__ float wsum[4];
    __shared__ float wdot[4][NCLS];
    __shared__ float cpart[NCLS];

    float ss = f0 * f0 + f1 * f1 + f2 * f2;
#pragma unroll
    for (int off = 32; off >= 1; off >>= 1) ss += __shfl_xor(ss, off, 64);
    if (lane == 0) wsum[wv] = ss;

    float dots[NCLS];
#pragma unroll
    for (int c = 0; c < NCLS; ++c) {
        const float* cl = classlat + c * HID;
        dots[c] = cl[t] * f0 + cl[t + 256] * f1 + cl[t + 512] * f2;
    }
#pragma unroll
    for (int c = 0; c < NCLS; ++c) {
        float v = dots[c];
#pragma unroll
        for (int off = 32; off >= 1; off >>= 1) v += __shfl_xor(v, off, 64);
        if (lane == 0) wdot[wv][c] = v;
    }
    __syncthreads();

    if (t < NCLS) {
        float tot  = wsum[0] + wsum[1] + wsum[2] + wsum[3];
        float invn = 1.0f / sqrtf(tot);
        float dot  = wdot[0][t] + wdot[1][t] + wdot[2][t] + wdot[3][t];
        float sim  = dot * invn;
        int   mv   = mask[(size_t)(b * NCLS + t) * NPATCH + n];
        cpart[t]   = (mv != 0) ? expf(sim * 2.0f) : 0.0f;
    }
    __syncthreads();
    if (t == 0) {
        float s = 0.f;
#pragma unroll
        for (int c = 0; c < NCLS; ++c) s += cpart[c];
        partial[p] = s;
    }
}

__global__ __launch_bounds__(256) void k_reduce(const float* __restrict__ partial,
                                                float* __restrict__ out) {
    int t = threadIdx.x;
    float s = 0.f;
    for (int i = t; i < NP; i += 256) s += partial[i];
#pragma unroll
    for (int off = 32; off >= 1; off >>= 1) s += __shfl_xor(s, off, 64);
    __shared__ float ws[4];
    if ((t & 63) == 0) ws[t >> 6] = s;
    __syncthreads();
    if (t == 0) out[0] = -logf(ws[0] + ws[1] + ws[2] + ws[3]);
}

// ---------------------------------------------------------------------------
extern "C" void kernel_launch(void* const* d_in, const int* in_sizes, int n_in,
                              void* d_out, int out_size, void* d_ws, size_t ws_size,
                              hipStream_t stream) {
    const float* x      = (const float*)d_in[0];
    const int*   mask   = (const int*)d_in[1];
    const float* conv_w = (const float*)d_in[2];
    const float* conv_b = (const float*)d_in[3];
    const float* latent = (const float*)d_in[4];
    float* out = (float*)d_out;

    // workspace layout (bytes) — x is read directly by k_gemm; no xb buffer
    const size_t wb_bytes   = (size_t)HID * KDIM * 2;          // 12,582,912
    const size_t pslice     = (size_t)NP * HID * 2;            // 3,145,728 (bf16)
    const size_t small_need = (size_t)NCLS * HID * 4 + NP * 4 + 256;

    char* base = (char*)d_ws;
    ushort* wb   = (ushort*)base;
    ushort* pbuf = (ushort*)(base + wb_bytes);

    int splitk = 1;
    const size_t fixed = wb_bytes + small_need;
    if (ws_size >= fixed + 8 * pslice)      splitk = 8;
    else if (ws_size >= fixed + 4 * pslice) splitk = 4;
    else if (ws_size >= fixed + 2 * pslice) splitk = 2;

    float* classlat = (float*)(base + wb_bytes + (size_t)splitk * pslice);
    float* partial  = classlat + NCLS * HID;

    k_prep<<<NB_CL + NB_W4, 256, 0, stream>>>(conv_w, latent, wb, classlat);

    dim3 g(NP / 128, HID / 128, splitk);
    switch (splitk) {
        case 8: k_gemm<8><<<g, 256, 0, stream>>>(x, wb, pbuf); break;
        case 4: k_gemm<4><<<g, 256, 0, stream>>>(x, wb, pbuf); break;
        case 2: k_gemm<2><<<g, 256, 0, stream>>>(x, wb, pbuf); break;
        default: k_gemm<1><<<g, 256, 0, stream>>>(x, wb, pbuf); break;
    }

    switch (splitk) {
        case 8: k_final<8><<<NP, 256, 0, stream>>>(pbuf, conv_b, classlat, mask, partial); break;
        case 4: k_final<4><<<NP, 256, 0, stream>>>(pbuf, conv_b, classlat, mask, partial); break;
        case 2: k_final<2><<<NP, 256, 0, stream>>>(pbuf, conv_b, classlat, mask, partial); break;
        default: k_final<1><<<NP, 256, 0, stream>>>(pbuf, conv_b, classlat, mask, partial); break;
    }
    k_reduce<<<1, 256, 0, stream>>>(partial, out);
}

// Round 11
// 90.117 us; speedup vs baseline: 1.0788x; 1.0788x over previous
//
#include <hip/hip_runtime.h>
#include <hip/hip_bf16.h>
#include <math.h>

// Problem constants
#define B_     2
#define CIN    32
#define HH     512
#define WW     512
#define HID    768
#define SZ     16
#define NPATCH 1024      // 32x32 patch grid
#define KDIM   8192      // CIN*SZ*SZ
#define NCLS   21
#define LAT    128
#define LC     2688      // LAT*NCLS
#define NP     (B_ * NPATCH)   // 2048 patch rows

// prep-kernel block ranges (classlat FIRST: longest serial chain)
#define NB_CL  63        // NCLS*3 : classlat (cls, 256-wide d-segment), norms inline
#define NB_W4  1536      // HID*KDIM/16/256  (4 float4 per thread)

typedef __attribute__((ext_vector_type(8))) short short8;   // 8 bf16 (4 VGPR)
typedef __attribute__((ext_vector_type(4))) float f32x4;

// RNE float->bf16
__device__ __forceinline__ ushort f2bf(float f) {
    union { float f; unsigned u; } v; v.f = f;
    unsigned r = (v.u + 0x7fff + ((v.u >> 16) & 1)) >> 16;
    return (ushort)r;
}
__device__ __forceinline__ float bf2f(ushort u) {
    union { unsigned u; float f; } v; v.u = (unsigned)u << 16;
    return v.f;
}

__device__ __forceinline__ void gload16(const void* g, void* l) {
    __builtin_amdgcn_global_load_lds(
        (const __attribute__((address_space(1))) unsigned int*)g,
        (__attribute__((address_space(3))) unsigned int*)l, 16, 0, 0);
}

// pack 2 f32 -> 1 u32 of 2 bf16 (RNE); compiler emits v_cvt_pk (m240)
__device__ __forceinline__ unsigned pk2bf(float a, float b) {
    union { __hip_bfloat162 h; unsigned u; } cv;
    cv.h = __float22bfloat162_rn(make_float2(a, b));
    return cv.u;
}

// ---------------------------------------------------------------------------
// Prep kernel (round-9/10 version, x untouched): conv_w + classlat, ~79MB.
// ---------------------------------------------------------------------------
__global__ __launch_bounds__(256) void k_prep(const float* __restrict__ w,
                                              const float* __restrict__ lat,
                                              ushort* __restrict__ wb,
                                              float* __restrict__ classlat) {
    const int bid = blockIdx.x;
    const int t   = threadIdx.x;

    if (bid < NB_CL) {
        // ---- classlat with inline row norms ----
        const int cls  = bid / 3;
        const int dseg = bid % 3;
        const int lane = t & 63, wvv = t >> 6;
        __shared__ float sc_sh[LAT];

        for (int q = 0; q < 32; q += 2) {
            int u0 = wvv * 32 + q;
            const float* r0 = lat + (size_t)(u0 * NCLS + cls) * HID;
            const float* r1 = lat + (size_t)((u0 + 1) * NCLS + cls) * HID;
            float s0 = 0.f, s1 = 0.f;
#pragma unroll
            for (int e = 0; e < HID / 64; ++e) {
                float a = r0[lane + e * 64]; s0 += a * a;
                float b2 = r1[lane + e * 64]; s1 += b2 * b2;
            }
#pragma unroll
            for (int off = 32; off >= 1; off >>= 1) {
                s0 += __shfl_xor(s0, off, 64);
                s1 += __shfl_xor(s1, off, 64);
            }
            if (lane == 0) {
                sc_sh[u0]     = 1.0f / (128.0f * sqrtf(s0));
                sc_sh[u0 + 1] = 1.0f / (128.0f * sqrtf(s1));
            }
        }
        __syncthreads();

        const float* src = lat + (size_t)cls * HID + dseg * 256 + t;
        float a = 0.f;
        for (int u0 = 0; u0 < LAT; u0 += 8) {
            float v[8];
#pragma unroll
            for (int q = 0; q < 8; ++q)
                v[q] = src[(size_t)(u0 + q) * (NCLS * HID)];
#pragma unroll
            for (int q = 0; q < 8; ++q) a += v[q] * sc_sh[u0 + q];
        }
        classlat[cls * HID + dseg * 256 + t] = a;
    } else {
        // ---- conv_w convert (coalesced both sides, 4 loads in flight) ----
        const int cb = bid - NB_CL;
        float4 vv[4];
#pragma unroll
        for (int k = 0; k < 4; ++k)
            vv[k] = *(const float4*)(w + ((size_t)cb * 1024 + k * 256 + t) * 4);
#pragma unroll
        for (int k = 0; k < 4; ++k) {
            ushort4 o;
            o.x = f2bf(vv[k].x); o.y = f2bf(vv[k].y);
            o.z = f2bf(vv[k].z); o.w = f2bf(vv[k].w);
            *(ushort4*)(wb + ((size_t)cb * 1024 + k * 256 + t) * 4) = o;
        }
    }
}

// ---------------------------------------------------------------------------
// MFMA GEMM, ROUND-11: f32 x direct, GLOBAL-ORDER A LDS layout.
// patch[p][d] = sum_k x-as-A[p][k] * wb[d][k],  k = c*256 + (i0+i_rel)*16 + j.
// 128x128 tile, BK=64, 4 waves (2x2), single-buffer 2-barrier loop (round-4
// shape), grid (16,6,SPLITK) = 768 @ splitk 8 = 3 blk/CU.
//
// A LDS = 32 regions x 1KB: region m = ph_rel*8 + i_rel*2 + h  (h = pw half),
// each region = [pw_rel 16][slot 4] 16B chunks in GLOBAL ORDER, so every
// gload16 wave-issue is 1KB CONTIGUOUS global (8 full 128B lines; the swizzle
// permutes 16B chunks only within their 64B group -> coalescing preserved).
// [rounds 8-10's gathers were 16-32x small-segment scatters — the defect.]
//
// Swizzle (hand-verified, 3 lane examples + full bank enumeration):
//   slot(pr, jq, i) = pr*4 + (jq ^ ((pr>>1)&3) ^ (i&3))
// Store (lane l, issue q,wv): pr=l>>2, J=l&3, i_rel=(wv>>1)+2*(q&1),
//   src_jq = J ^ ((pr>>1)&3) ^ i_rel  ->  laneA ^ 8*(q&1) address trick.
// Read (fr,fq,s): A ds_read_b128 lands 8 lanes/bank-quad = CONFLICT-FREE
//   minimum; addr_hi = addr_lo ^ 4 (f32).
// B: round-4 verbatim (bf16 wb, gload16 + XOR swizzle, [128][64]).
// T1 bijective XCD remap; slice bz covers 4 channels; A panel/bx = 512KB
// re-read by 6 consecutive same-XCD by-blocks (L2-hit after first).
// Output layout: pbuf[p][z][d] (unchanged, round-10-verified shell).
// ---------------------------------------------------------------------------
template <int SPLITK>
__global__ __launch_bounds__(256) void k_gemm(const float* __restrict__ x,
                                              const ushort* __restrict__ wb,
                                              ushort* __restrict__ pbuf) {
    constexpr int KS = KDIM / SPLITK;
    __shared__ float  Af[32 * 256];    // 32 KB : 32 regions x 256 f32
    __shared__ ushort Bls[128 * 64];   // 16 KB

    // ---- T1 remap: grid (16, 6, SPLITK), nwg = 96*SPLITK (always %8==0) ----
    const int flat = blockIdx.x + 16 * (blockIdx.y + 6 * blockIdx.z);
    constexpr int nwg = 96 * SPLITK;
    const int wg = (flat & 7) * (nwg >> 3) + (flat >> 3);
    const int bz = wg / 96;
    const int rr = wg - bz * 96;
    const int by = rr % 6;       // by-fastest: consecutive blocks share the A panel
    const int bx = rr / 6;       // 0..15

    const int tid  = threadIdx.x;
    const int wv   = tid >> 6;         // 0..3
    const int lane = tid & 63;
    const int wm   = (wv >> 1) * 64;
    const int wn   = (wv & 1) * 64;

    const int bxb = bx >> 3;           // batch index
    const int ph0 = (bx & 7) * 4;      // first ph of this tile (4 ph rows)

    const size_t bbase = ((size_t)by * 128) * KDIM + (size_t)bz * KS;

    // ---- B staging lanes (round-4 verbatim) ----
    const int srow  = wv * 8 + (lane >> 3);                    // + q*32
    const int skoff = (((lane & 7) ^ (lane >> 3)) * 8);        // swizzled src elem

    // ---- A staging: per-lane source offset (f32), global-order layout ----
    // lane l: pr = l>>2 (16B chunk row), J = l&3 (slot);  w2 = wv>>1, h = wv&1
    // content jq at slot J: jq = J ^ ((pr>>1)&3) ^ i_rel, i_rel = w2 + 2*(q&1)
    {
    }
    const int l_   = lane;
    const int pr_  = l_ >> 2, Jl_ = l_ & 3;
    const int w2_  = (wv >> 1) & 1, h_ = wv & 1;
    const int jqb_ = Jl_ ^ ((pr_ >> 1) & 3) ^ w2_;
    const size_t laneA = (size_t)pr_ * 16 + (size_t)h_ * 256
                       + (size_t)w2_ * 512 + (size_t)jqb_ * 4;
    // per q: src = xs + (q>>1)*8192 + (q&1)*1024 + (laneA ^ (8*(q&1)))
    // (jq bit1 flip == f32-index XOR 8; laneA has no other bit-3 content)

    f32x4 acc[4][4];
#pragma unroll
    for (int m = 0; m < 4; ++m)
#pragma unroll
        for (int n = 0; n < 4; ++n) acc[m][n] = (f32x4)(0.f);

    const int fr = lane & 15, fq = lane >> 4;
    const int frx = (fr & 7) * 8;       // B read-side XOR (ushort elems)
    const int fq1 = fq >> 1;
    const int Jb  = ((fq & 1) * 2) ^ ((fr >> 1) & 3) ^ fq1;   // 2-bit
    const int rb_lane = fr * 16 + fq1 * 512;                  // f32

    for (int kk = 0; kk < KS; kk += 64) {
        const int gk = bz * KS + kk;            // global k, multiple of 64
        const int c  = gk >> 8;                 // input channel
        const int i0 = (gk >> 4) & 15;          // 0,4,8,12
        const float* xs = x + (size_t)bxb * 8388608 + (size_t)c * 262144
                        + (size_t)(ph0 * 16 + i0) * 512;

        // ---- A staging: 8 issues/wave, each 1KB CONTIGUOUS global ----
#pragma unroll
        for (int q = 0; q < 8; ++q) {
            const float* src = xs + (q >> 1) * 8192 + (q & 1) * 1024
                             + (laneA ^ (size_t)((q & 1) * 8));
            gload16(src, &Af[(q * 4 + wv) * 256]);
        }
        // ---- B staging (round-4 verbatim) ----
#pragma unroll
        for (int q = 0; q < 4; ++q) {
            const int row = q * 32 + srow;
            gload16(&wb[bbase + (size_t)row * KDIM + kk + skoff],
                    &Bls[q * 2048 + wv * 512]);
        }
        __syncthreads();   // drains vmcnt: tiles ready

#pragma unroll
        for (int s = 0; s < 2; ++s) {
            short8 af[4], bf[4];
#pragma unroll
            for (int fm = 0; fm < 4; ++fm) {
                const int pb    = wm + fm * 16;
                const int rbase = (pb >> 5) * 2048 + ((pb >> 4) & 1) * 256 + rb_lane;
                const int alo   = rbase + s * 1024 + ((Jb ^ (s << 1)) << 2);
                f32x4 lo = *(const f32x4*)&Af[alo];
                f32x4 hi = *(const f32x4*)&Af[alo ^ 4];
                union { unsigned u[4]; short8 s8; } cv;
                cv.u[0] = pk2bf(lo[0], lo[1]);
                cv.u[1] = pk2bf(lo[2], lo[3]);
                cv.u[2] = pk2bf(hi[0], hi[1]);
                cv.u[3] = pk2bf(hi[2], hi[3]);
                af[fm] = cv.s8;
            }
#pragma unroll
            for (int n = 0; n < 4; ++n)
                bf[n] = *(const short8*)&Bls[(wn + n * 16 + fr) * 64
                                             + ((s * 32 + fq * 8) ^ frx)];
#pragma unroll
            for (int m = 0; m < 4; ++m)
#pragma unroll
                for (int n = 0; n < 4; ++n)
                    acc[m][n] = __builtin_amdgcn_mfma_f32_16x16x32_bf16(af[m], bf[n], acc[m][n], 0, 0, 0);
        }
        __syncthreads();
    }

#pragma unroll
    for (int m = 0; m < 4; ++m) {
#pragma unroll
        for (int n = 0; n < 4; ++n) {
            int col = by * 128 + wn + n * 16 + fr;
#pragma unroll
            for (int j = 0; j < 4; ++j) {
                int row = bx * 128 + wm + m * 16 + fq * 4 + j;
                pbuf[((size_t)row * SPLITK + bz) * HID + col] = f2bf(acc[m][n][j]);
            }
        }
    }
}

// ---------------------------------------------------------------------------
// Per-patch epilogue: stage the patch's contiguous [SPLITK][HID] bf16 partials
// into LDS (coalesced 16B loads), sum + bias -> norm -> 21 dots ->
// masked exp(2*sim) -> partial[p].
// ---------------------------------------------------------------------------
template <int SPLITK>
__global__ __launch_bounds__(256) void k_final(const ushort* __restrict__ pbuf,
                                               const float* __restrict__ conv_b,
                                               const float* __restrict__ classlat,
                                               const int* __restrict__ mask,
                                               float* __restrict__ partial) {
    const int p = blockIdx.x;        // 0..2047
    const int b = p >> 10, n = p & 1023;
    const int t = threadIdx.x;
    const int lane = t & 63, wv = t >> 6;

    __shared__ ushort sh[SPLITK * HID];
    const ushort* pb = pbuf + (size_t)p * (SPLITK * HID);
    for (int i = t; i < SPLITK * HID / 8; i += 256)
        *(short8*)&sh[i * 8] = *(const short8*)&pb[(size_t)i * 8];
    __syncthreads();

    float f0 = conv_b[t], f1 = conv_b[t + 256], f2 = conv_b[t + 512];
#pragma unroll
    for (int z = 0; z < SPLITK; ++z) {
        f0 += bf2f(sh[z * HID + t]);
        f1 += bf2f(sh[z * HID + t + 256]);
        f2 += bf2f(sh[z * HID + t + 512]);
    }

    __shared__ float wsum[4];
    __shared__ float wdot[4][NCLS];
    __shared__ float cpart[NCLS];

    float ss = f0 * f0 + f1 * f1 + f2 * f2;
#pragma unroll
    for (int off = 32; off >= 1; off >>= 1) ss += __shfl_xor(ss, off, 64);
    if (lane == 0) wsum[wv] = ss;

    float dots[NCLS];
#pragma unroll
    for (int c = 0; c < NCLS; ++c) {
        const float* cl = classlat + c * HID;
        dots[c] = cl[t] * f0 + cl[t + 256] * f1 + cl[t + 512] * f2;
    }
#pragma unroll
    for (int c = 0; c < NCLS; ++c) {
        float v = dots[c];
#pragma unroll
        for (int off = 32; off >= 1; off >>= 1) v += __shfl_xor(v, off, 64);
        if (lane == 0) wdot[wv][c] = v;
    }
    __syncthreads();

    if (t < NCLS) {
        float tot  = wsum[0] + wsum[1] + wsum[2] + wsum[3];
        float invn = 1.0f / sqrtf(tot);
        float dot  = wdot[0][t] + wdot[1][t] + wdot[2][t] + wdot[3][t];
        float sim  = dot * invn;
        int   mv   = mask[(size_t)(b * NCLS + t) * NPATCH + n];
        cpart[t]   = (mv != 0) ? expf(sim * 2.0f) : 0.0f;
    }
    __syncthreads();
    if (t == 0) {
        float s = 0.f;
#pragma unroll
        for (int c = 0; c < NCLS; ++c) s += cpart[c];
        partial[p] = s;
    }
}

__global__ __launch_bounds__(256) void k_reduce(const float* __restrict__ partial,
                                                float* __restrict__ out) {
    int t = threadIdx.x;
    float s = 0.f;
    for (int i = t; i < NP; i += 256) s += partial[i];
#pragma unroll
    for (int off = 32; off >= 1; off >>= 1) s += __shfl_xor(s, off, 64);
    __shared__ float ws[4];
    if ((t & 63) == 0) ws[t >> 6] = s;
    __syncthreads();
    if (t == 0) out[0] = -logf(ws[0] + ws[1] + ws[2] + ws[3]);
}

// ---------------------------------------------------------------------------
extern "C" void kernel_launch(void* const* d_in, const int* in_sizes, int n_in,
                              void* d_out, int out_size, void* d_ws, size_t ws_size,
                              hipStream_t stream) {
    const float* x      = (const float*)d_in[0];
    const int*   mask   = (const int*)d_in[1];
    const float* conv_w = (const float*)d_in[2];
    const float* conv_b = (const float*)d_in[3];
    const float* latent = (const float*)d_in[4];
    float* out = (float*)d_out;

    // workspace layout (bytes) — x is read directly by k_gemm; no xb buffer
    const size_t wb_bytes   = (size_t)HID * KDIM * 2;          // 12,582,912
    const size_t pslice     = (size_t)NP * HID * 2;            // 3,145,728 (bf16)
    const size_t small_need = (size_t)NCLS * HID * 4 + NP * 4 + 256;

    char* base = (char*)d_ws;
    ushort* wb   = (ushort*)base;
    ushort* pbuf = (ushort*)(base + wb_bytes);

    int splitk = 1;
    const size_t fixed = wb_bytes + small_need;
    if (ws_size >= fixed + 8 * pslice)      splitk = 8;
    else if (ws_size >= fixed + 4 * pslice) splitk = 4;
    else if (ws_size >= fixed + 2 * pslice) splitk = 2;

    float* classlat = (float*)(base + wb_bytes + (size_t)splitk * pslice);
    float* partial  = classlat + NCLS * HID;

    k_prep<<<NB_CL + NB_W4, 256, 0, stream>>>(conv_w, latent, wb, classlat);

    dim3 g(NP / 128, HID / 128, splitk);
    switch (splitk) {
        case 8: k_gemm<8><<<g, 256, 0, stream>>>(x, wb, pbuf); break;
        case 4: k_gemm<4><<<g, 256, 0, stream>>>(x, wb, pbuf); break;
        case 2: k_gemm<2><<<g, 256, 0, stream>>>(x, wb, pbuf); break;
        default: k_gemm<1><<<g, 256, 0, stream>>>(x, wb, pbuf); break;
    }

    switch (splitk) {
        case 8: k_final<8><<<NP, 256, 0, stream>>>(pbuf, conv_b, classlat, mask, partial); break;
        case 4: k_final<4><<<NP, 256, 0, stream>>>(pbuf, conv_b, classlat, mask, partial); break;
        case 2: k_final<2><<<NP, 256, 0, stream>>>(pbuf, conv_b, classlat, mask, partial); break;
        default: k_final<1><<<NP, 256, 0, stream>>>(pbuf, conv_b, classlat, mask, partial); break;
    }
    k_reduce<<<1, 256, 0, stream>>>(partial, out);
}

// Round 12
// 88.040 us; speedup vs baseline: 1.1042x; 1.0236x over previous
//
#include <hip/hip_runtime.h>
#include <hip/hip_bf16.h>
#include <math.h>

// Problem constants
#define B_     2
#define CIN    32
#define HH     512
#define WW     512
#define HID    768
#define SZ     16
#define NPATCH 1024      // 32x32 patch grid
#define KDIM   8192      // CIN*SZ*SZ
#define NCLS   21
#define LAT    128
#define LC     2688      // LAT*NCLS
#define NP     (B_ * NPATCH)   // 2048 patch rows

// prep-kernel block ranges (classlat FIRST: longest serial chain)
#define NB_CL  63        // NCLS*3 : classlat (cls, 256-wide d-segment), norms inline
#define NB_W4  1536      // HID*KDIM/16/256  (4 float4 per thread)

typedef __attribute__((ext_vector_type(8))) short short8;   // 8 bf16 (4 VGPR)
typedef __attribute__((ext_vector_type(4))) float f32x4;

// RNE float->bf16
__device__ __forceinline__ ushort f2bf(float f) {
    union { float f; unsigned u; } v; v.f = f;
    unsigned r = (v.u + 0x7fff + ((v.u >> 16) & 1)) >> 16;
    return (ushort)r;
}
__device__ __forceinline__ float bf2f(ushort u) {
    union { unsigned u; float f; } v; v.u = (unsigned)u << 16;
    return v.f;
}

__device__ __forceinline__ void gload16(const void* g, void* l) {
    __builtin_amdgcn_global_load_lds(
        (const __attribute__((address_space(1))) unsigned int*)g,
        (__attribute__((address_space(3))) unsigned int*)l, 16, 0, 0);
}

// pack 2 f32 -> 1 u32 of 2 bf16 (RNE); compiler emits v_cvt_pk (m240)
__device__ __forceinline__ unsigned pk2bf(float a, float b) {
    union { __hip_bfloat162 h; unsigned u; } cv;
    cv.h = __float22bfloat162_rn(make_float2(a, b));
    return cv.u;
}

// ---------------------------------------------------------------------------
// Prep kernel (x untouched): conv_w + classlat, ~79MB streaming.
// ---------------------------------------------------------------------------
__global__ __launch_bounds__(256) void k_prep(const float* __restrict__ w,
                                              const float* __restrict__ lat,
                                              ushort* __restrict__ wb,
                                              float* __restrict__ classlat) {
    const int bid = blockIdx.x;
    const int t   = threadIdx.x;

    if (bid < NB_CL) {
        // ---- classlat with inline row norms ----
        const int cls  = bid / 3;
        const int dseg = bid % 3;
        const int lane = t & 63, wvv = t >> 6;
        __shared__ float sc_sh[LAT];

        for (int q = 0; q < 32; q += 2) {
            int u0 = wvv * 32 + q;
            const float* r0 = lat + (size_t)(u0 * NCLS + cls) * HID;
            const float* r1 = lat + (size_t)((u0 + 1) * NCLS + cls) * HID;
            float s0 = 0.f, s1 = 0.f;
#pragma unroll
            for (int e = 0; e < HID / 64; ++e) {
                float a = r0[lane + e * 64]; s0 += a * a;
                float b2 = r1[lane + e * 64]; s1 += b2 * b2;
            }
#pragma unroll
            for (int off = 32; off >= 1; off >>= 1) {
                s0 += __shfl_xor(s0, off, 64);
                s1 += __shfl_xor(s1, off, 64);
            }
            if (lane == 0) {
                sc_sh[u0]     = 1.0f / (128.0f * sqrtf(s0));
                sc_sh[u0 + 1] = 1.0f / (128.0f * sqrtf(s1));
            }
        }
        __syncthreads();

        const float* src = lat + (size_t)cls * HID + dseg * 256 + t;
        float a = 0.f;
        for (int u0 = 0; u0 < LAT; u0 += 8) {
            float v[8];
#pragma unroll
            for (int q = 0; q < 8; ++q)
                v[q] = src[(size_t)(u0 + q) * (NCLS * HID)];
#pragma unroll
            for (int q = 0; q < 8; ++q) a += v[q] * sc_sh[u0 + q];
        }
        classlat[cls * HID + dseg * 256 + t] = a;
    } else {
        // ---- conv_w convert (coalesced both sides, 4 loads in flight) ----
        const int cb = bid - NB_CL;
        float4 vv[4];
#pragma unroll
        for (int k = 0; k < 4; ++k)
            vv[k] = *(const float4*)(w + ((size_t)cb * 1024 + k * 256 + t) * 4);
#pragma unroll
        for (int k = 0; k < 4; ++k) {
            ushort4 o;
            o.x = f2bf(vv[k].x); o.y = f2bf(vv[k].y);
            o.z = f2bf(vv[k].z); o.w = f2bf(vv[k].w);
            *(ushort4*)(wb + ((size_t)cb * 1024 + k * 256 + t) * 4) = o;
        }
    }
}

// ---------------------------------------------------------------------------
// MFMA GEMM, ROUND-12: f32 x direct; region-padded A LDS with enumerated
// conflict-free 16B-chunk swizzle (round-11's 11M conflicts = wrong slot fn).
//
// A LDS: 32 regions (m = ph_rel*8 + i_rel*2 + h) x 260 f32 (1KB content +
// 16B pad BETWEEN regions; stride 1040B).  Region content: [pw_rel 16][j 16]
// f32 = one half-row of x, global-contiguous.  Issue (q,wv) fills region
// m = (q>>1)*8 + (q&1)*4 + wv; LDS dest contiguous 1KB (m104-compliant).
// Chunk-quad of (m,c) = (m+c)&7  (65 chunks/region, 65 mod 8 = 1).
//
// Swizzle (FULLY ENUMERATED, 64 lanes of one instr -> exactly 8 lanes/quad):
//   read  chunk c = fr*4 + ((jq ^ (fr>>1)) & 3),  jq = (fq&1)*2 (+1 hi)
//   store lane l -> chunk l, source global chunk g = (l&~3)|(((l&3)^(l>>3))&3)
//   (bijection within the 1KB issue -> 8 full 128B lines, coalescing kept;
//    per-lane gload_lds SOURCE is legal per m104/m173)
// Round-trip verified (fr=5,fq=3 lane).
//
// B: round-4 verbatim (bf16 wb, gload16 + XOR swizzle, [128][64]).
// Loop: 128x128 tile, BK=64, 4 waves, 2 barriers/K-step, grid (16,6,SPLITK)
// = 768 @ splitk 8 = 3 blk/CU.  T1 bijective XCD remap; slice bz covers 4
// channels (x HBM-read once); A panel/bx = 512KB L2-resident across by=6.
// Output: pbuf[p][z][d] (round-10/11-verified shell).
// ---------------------------------------------------------------------------
template <int SPLITK>
__global__ __launch_bounds__(256) void k_gemm(const float* __restrict__ x,
                                              const ushort* __restrict__ wb,
                                              ushort* __restrict__ pbuf) {
    constexpr int KS = KDIM / SPLITK;
    __shared__ float  Af[32 * 260];    // 33,280 B
    __shared__ ushort Bls[128 * 64];   // 16,384 B  (total 49,664 -> 3 blk/CU)

    // ---- T1 remap: grid (16, 6, SPLITK), nwg = 96*SPLITK (always %8==0) ----
    const int flat = blockIdx.x + 16 * (blockIdx.y + 6 * blockIdx.z);
    constexpr int nwg = 96 * SPLITK;
    const int wg = (flat & 7) * (nwg >> 3) + (flat >> 3);
    const int bz = wg / 96;
    const int rr = wg - bz * 96;
    const int by = rr % 6;       // by-fastest: consecutive blocks share the A panel
    const int bx = rr / 6;       // 0..15

    const int tid  = threadIdx.x;
    const int wv   = tid >> 6;         // 0..3
    const int lane = tid & 63;
    const int wm   = (wv >> 1) * 64;
    const int wn   = (wv & 1) * 64;

    const int bxb = bx >> 3;           // batch index
    const int ph0 = (bx & 7) * 4;      // first ph of this tile (4 ph rows)

    const size_t bbase = ((size_t)by * 128) * KDIM + (size_t)bz * KS;

    // ---- B staging lanes (round-4 verbatim) ----
    const int srow  = wv * 8 + (lane >> 3);                    // + q*32
    const int skoff = (((lane & 7) ^ (lane >> 3)) * 8);        // swizzled src elem

    // ---- A store: per-lane global offset (f32), q/wv-invariant ----
    // lane l writes LDS chunk l; source global chunk g = (l&~3)|(((l&3)^(l>>3))&3)
    const int gl = ((lane >> 2) * 16) + ((((lane & 3) ^ (lane >> 3)) & 3) * 4);

    f32x4 acc[4][4];
#pragma unroll
    for (int m = 0; m < 4; ++m)
#pragma unroll
        for (int n = 0; n < 4; ++n) acc[m][n] = (f32x4)(0.f);

    const int fr = lane & 15, fq = lane >> 4;
    const int frx = (fr & 7) * 8;       // B read-side XOR (ushort elems)
    // ---- A read per-lane constants ----
    const int jql      = (fq & 1) * 2;
    const int c_lo     = fr * 4 + ((jql ^ (fr >> 1)) & 3);        // chunk
    const int c_hi     = c_lo ^ 1;                                 // jq+1
    const int i_fq     = fq >> 1;
    const int ph_part  = wm >> 5;       // 0 or 2

    for (int kk = 0; kk < KS; kk += 64) {
        const int gk = bz * KS + kk;            // global k, multiple of 64
        const int c  = gk >> 8;                 // input channel
        const int i0 = (gk >> 4) & 15;          // 0,4,8,12
        const float* xs = x + (size_t)bxb * 8388608 + (size_t)c * 262144
                        + (size_t)(ph0 * 16 + i0) * 512;

        // ---- A staging: 8 issues/wave, each 1KB global (permuted-covering) ----
#pragma unroll
        for (int q = 0; q < 8; ++q) {
            const float* src = xs + (q >> 1) * 8192
                             + ((q & 1) * 2 + (wv >> 1)) * 512
                             + (wv & 1) * 256 + gl;
            const int m = (q >> 1) * 8 + (q & 1) * 4 + wv;
            gload16(src, &Af[m * 260]);
        }
        // ---- B staging (round-4 verbatim) ----
#pragma unroll
        for (int q = 0; q < 4; ++q) {
            const int row = q * 32 + srow;
            gload16(&wb[bbase + (size_t)row * KDIM + kk + skoff],
                    &Bls[q * 2048 + wv * 512]);
        }
        __syncthreads();   // drains vmcnt: tiles ready

#pragma unroll
        for (int s = 0; s < 2; ++s) {
            short8 af[4], bf[4];
#pragma unroll
            for (int fm = 0; fm < 4; ++fm) {
                const int m   = (ph_part + (fm >> 1)) * 8
                              + (s * 2 + i_fq) * 2 + (fm & 1);
                const int mb  = m * 260;
                f32x4 lo = *(const f32x4*)&Af[mb + c_lo * 4];
                f32x4 hi = *(const f32x4*)&Af[mb + c_hi * 4];
                union { unsigned u[4]; short8 s8; } cv;
                cv.u[0] = pk2bf(lo[0], lo[1]);
                cv.u[1] = pk2bf(lo[2], lo[3]);
                cv.u[2] = pk2bf(hi[0], hi[1]);
                cv.u[3] = pk2bf(hi[2], hi[3]);
                af[fm] = cv.s8;
            }
#pragma unroll
            for (int n = 0; n < 4; ++n)
                bf[n] = *(const short8*)&Bls[(wn + n * 16 + fr) * 64
                                             + ((s * 32 + fq * 8) ^ frx)];
#pragma unroll
            for (int m = 0; m < 4; ++m)
#pragma unroll
                for (int n = 0; n < 4; ++n)
                    acc[m][n] = __builtin_amdgcn_mfma_f32_16x16x32_bf16(af[m], bf[n], acc[m][n], 0, 0, 0);
        }
        __syncthreads();
    }

#pragma unroll
    for (int m = 0; m < 4; ++m) {
#pragma unroll
        for (int n = 0; n < 4; ++n) {
            int col = by * 128 + wn + n * 16 + fr;
#pragma unroll
            for (int j = 0; j < 4; ++j) {
                int row = bx * 128 + wm + m * 16 + fq * 4 + j;
                pbuf[((size_t)row * SPLITK + bz) * HID + col] = f2bf(acc[m][n][j]);
            }
        }
    }
}

// ---------------------------------------------------------------------------
// Per-patch epilogue: stage the patch's contiguous [SPLITK][HID] bf16 partials
// into LDS (coalesced 16B loads), sum + bias -> norm -> 21 dots ->
// masked exp(2*sim) -> partial[p].
// ---------------------------------------------------------------------------
template <int SPLITK>
__global__ __launch_bounds__(256) void k_final(const ushort* __restrict__ pbuf,
                                               const float* __restrict__ conv_b,
                                               const float* __restrict__ classlat,
                                               const int* __restrict__ mask,
                                               float* __restrict__ partial) {
    const int p = blockIdx.x;        // 0..2047
    const int b = p >> 10, n = p & 1023;
    const int t = threadIdx.x;
    const int lane = t & 63, wv = t >> 6;

    __shared__ ushort sh[SPLITK * HID];
    const ushort* pb = pbuf + (size_t)p * (SPLITK * HID);
    for (int i = t; i < SPLITK * HID / 8; i += 256)
        *(short8*)&sh[i * 8] = *(const short8*)&pb[(size_t)i * 8];
    __syncthreads();

    float f0 = conv_b[t], f1 = conv_b[t + 256], f2 = conv_b[t + 512];
#pragma unroll
    for (int z = 0; z < SPLITK; ++z) {
        f0 += bf2f(sh[z * HID + t]);
        f1 += bf2f(sh[z * HID + t + 256]);
        f2 += bf2f(sh[z * HID + t + 512]);
    }

    __shared__ float wsum[4];
    __shared__ float wdot[4][NCLS];
    __shared__ float cpart[NCLS];

    float ss = f0 * f0 + f1 * f1 + f2 * f2;
#pragma unroll
    for (int off = 32; off >= 1; off >>= 1) ss += __shfl_xor(ss, off, 64);
    if (lane == 0) wsum[wv] = ss;

    float dots[NCLS];
#pragma unroll
    for (int c = 0; c < NCLS; ++c) {
        const float* cl = classlat + c * HID;
        dots[c] = cl[t] * f0 + cl[t + 256] * f1 + cl[t + 512] * f2;
    }
#pragma unroll
    for (int c = 0; c < NCLS; ++c) {
        float v = dots[c];
#pragma unroll
        for (int off = 32; off >= 1; off >>= 1) v += __shfl_xor(v, off, 64);
        if (lane == 0) wdot[wv][c] = v;
    }
    __syncthreads();

    if (t < NCLS) {
        float tot  = wsum[0] + wsum[1] + wsum[2] + wsum[3];
        float invn = 1.0f / sqrtf(tot);
        float dot  = wdot[0][t] + wdot[1][t] + wdot[2][t] + wdot[3][t];
        float sim  = dot * invn;
        int   mv   = mask[(size_t)(b * NCLS + t) * NPATCH + n];
        cpart[t]   = (mv != 0) ? expf(sim * 2.0f) : 0.0f;
    }
    __syncthreads();
    if (t == 0) {
        float s = 0.f;
#pragma unroll
        for (int c = 0; c < NCLS; ++c) s += cpart[c];
        partial[p] = s;
    }
}

__global__ __launch_bounds__(256) void k_reduce(const float* __restrict__ partial,
                                                float* __restrict__ out) {
    int t = threadIdx.x;
    float s = 0.f;
    for (int i = t; i < NP; i += 256) s += partial[i];
#pragma unroll
    for (int off = 32; off >= 1; off >>= 1) s += __shfl_xor(s, off, 64);
    __shared__ float ws[4];
    if ((t & 63) == 0) ws[t >> 6] = s;
    __syncthreads();
    if (t == 0) out[0] = -logf(ws[0] + ws[1] + ws[2] + ws[3]);
}

// ---------------------------------------------------------------------------
extern "C" void kernel_launch(void* const* d_in, const int* in_sizes, int n_in,
                              void* d_out, int out_size, void* d_ws, size_t ws_size,
                              hipStream_t stream) {
    const float* x      = (const float*)d_in[0];
    const int*   mask   = (const int*)d_in[1];
    const float* conv_w = (const float*)d_in[2];
    const float* conv_b = (const float*)d_in[3];
    const float* latent = (const float*)d_in[4];
    float* out = (float*)d_out;

    // workspace layout (bytes) — x is read directly by k_gemm; no xb buffer
    const size_t wb_bytes   = (size_t)HID * KDIM * 2;          // 12,582,912
    const size_t pslice     = (size_t)NP * HID * 2;            // 3,145,728 (bf16)
    const size_t small_need = (size_t)NCLS * HID * 4 + NP * 4 + 256;

    char* base = (char*)d_ws;
    ushort* wb   = (ushort*)base;
    ushort* pbuf = (ushort*)(base + wb_bytes);

    int splitk = 1;
    const size_t fixed = wb_bytes + small_need;
    if (ws_size >= fixed + 8 * pslice)      splitk = 8;
    else if (ws_size >= fixed + 4 * pslice) splitk = 4;
    else if (ws_size >= fixed + 2 * pslice) splitk = 2;

    float* classlat = (float*)(base + wb_bytes + (size_t)splitk * pslice);
    float* partial  = classlat + NCLS * HID;

    k_prep<<<NB_CL + NB_W4, 256, 0, stream>>>(conv_w, latent, wb, classlat);

    dim3 g(NP / 128, HID / 128, splitk);
    switch (splitk) {
        case 8: k_gemm<8><<<g, 256, 0, stream>>>(x, wb, pbuf); break;
        case 4: k_gemm<4><<<g, 256, 0, stream>>>(x, wb, pbuf); break;
        case 2: k_gemm<2><<<g, 256, 0, stream>>>(x, wb, pbuf); break;
        default: k_gemm<1><<<g, 256, 0, stream>>>(x, wb, pbuf); break;
    }

    switch (splitk) {
        case 8: k_final<8><<<NP, 256, 0, stream>>>(pbuf, conv_b, classlat, mask, partial); break;
        case 4: k_final<4><<<NP, 256, 0, stream>>>(pbuf, conv_b, classlat, mask, partial); break;
        case 2: k_final<2><<<NP, 256, 0, stream>>>(pbuf, conv_b, classlat, mask, partial); break;
        default: k_final<1><<<NP, 256, 0, stream>>>(pbuf, conv_b, classlat, mask, partial); break;
    }
    k_reduce<<<1, 256, 0, stream>>>(partial, out);
}